// Round 10
// baseline (171.931 us; speedup 1.0000x reference)
//
#include <hip/hip_runtime.h>
#include <math.h>

#define IMG   512
#define NFILT 32
#define PI_F  3.14159265358979323846f
#define GS    104      // LDS row stride in halves (208 B)
#define TBUF  (64 * GS)

typedef _Float16 v8h __attribute__((ext_vector_type(8)));
typedef float    v4f __attribute__((ext_vector_type(4)));

__device__ __forceinline__ unsigned pkrtz(float a, float b) {
    typedef __fp16 f16x2 __attribute__((ext_vector_type(2)));
    union { f16x2 h; unsigned u; } x;
    x.h = __builtin_amdgcn_cvt_pkrtz(a, b);
    return x.u;
}

template <int CTRL>
__device__ __forceinline__ float dpp_add(float v) {
    int t = __builtin_amdgcn_update_dpp(0, __float_as_int(v), CTRL, 0xf, 0xf, true);
    return v + __int_as_float(t);
}

#if __has_builtin(__builtin_amdgcn_sqrtf)
__device__ __forceinline__ float fsqrt(float x) { return __builtin_amdgcn_sqrtf(x); }
#else
__device__ __forceinline__ float fsqrt(float x) { return sqrtf(x); }
#endif

// Loop barrier: only LDS ops must drain; global prefetch loads stay in flight.
__device__ __forceinline__ void bar_lgkm() {
    asm volatile("s_waitcnt lgkmcnt(0)\n\ts_barrier" ::: "memory");
}

__device__ __forceinline__ v8h ldfrag(const uint4* p) {
    union { uint4 u; v8h h; } x; x.u = *p; return x.h;
}

// ---------------------------------------------------------------------------
// tabs layout (dwords): [filter:32][table:5][copy:8][block:20][dw:4]
//   tables: 0 g_re, 1 g_im, 2 f_re, 3 f_im, 4 -f_im
// ---------------------------------------------------------------------------
__global__ void make_tables(unsigned* __restrict__ tabs) {
    __shared__ _Float16 P[5][168];      // P[tbl][p] = tap(p-64), zero-padded
    const int fo = blockIdx.x;
    const int tid = threadIdx.x;
    for (int e = tid; e < 5 * 168; e += 256) ((_Float16*)P)[e] = (_Float16)0.0f;
    __syncthreads();
    if (tid < 160) {
        int tbl = tid >> 5, t = tid & 31;
        int s = (fo >> 3) + 1, o = fo & 7;
        float theta = (float)o * (PI_F / 7.0f);      // linspace(0, pi, 8)
        float sf = (float)s * 2.0f;                  // scale * SIGMA
        float kf = 2.0f * PI_F / ((float)s * sf);
        float a = kf * cosf(theta), b = kf * sinf(theta);
        float d = (float)(t - 16);
        float env = expf(-0.5f * d * d / (sf * sf));
        float v;
        switch (tbl) {
            case 0: v =  env * cosf(b * d); break;
            case 1: v =  env * sinf(b * d); break;
            case 2: v =  env * cosf(a * d); break;
            case 3: v =  env * sinf(a * d); break;
            default: v = -env * sinf(a * d); break;
        }
        P[tbl][t + 64] = (_Float16)v;
    }
    __syncthreads();
    unsigned* dst = tabs + (size_t)fo * 3200;
    for (int e = tid; e < 3200; e += 256) {
        int tbl  = e / 640;  int rem2 = e - tbl * 640;
        int copy = rem2 / 80; int idw = rem2 - copy * 80;
        int p0 = (idw >> 2) * 8 + copy + (idw & 3) * 2;   // = t0 + 64
        union { unsigned u; _Float16 h[2]; } p;
        p.h[0] = P[tbl][p0];
        p.h[1] = P[tbl][p0 + 1];
        dst[e] = p.u;
    }
}

// ---------------------------------------------------------------------------
// R20b (R9 failed to compile: init-lists of pointers into __shared__ produce
// an addrspacecast static initializer that gfx950 rejects; T base pointers
// are now computed arithmetically per use — no other change):
// R5's minimal-MFMA dbuf pipeline (28 MFMA/wave-pair, 1 barrier/pair) at
// HIGHER OCCUPANCY.  R19's counters proved MFMA cost ~ instruction count and
// that barriers/conflicts were NOT the residual; theory: R5's gap is latency
// under-hidden at 2 blocks/CU.
//   - fsplit=2: grid 1024 (8n x 64 tiles x 2), each block does 8 pairs
//   - gray LDS aliased with T buffers (gray dead after Agray hoist + S0):
//     LDS 75 -> 53 KB => 3 blocks/CU co-resident (24 waves, was 16)
//   - S1 stored direct to global (drop s1st + epilogue)
//   - barrier between gray-readers (hoist/S0) and aliased T[0] writes
// ---------------------------------------------------------------------------
__launch_bounds__(512, 6)
__global__ void conv_kernel(const float* __restrict__ x,
                            const uint4* __restrict__ tabs,
                            float* __restrict__ s0out,
                            float* __restrict__ s1out) {
    // Union region: 4 T half-buffers of TBUF halves = 53248 B total.
    // Layout: [Tre0 | Tim0 | Tre1 | Tim1]; gray (96*GS) aliases Tre0+Tim0.
    __shared__ _Float16 U[4 * TBUF];
    _Float16* gray = U;

    const int bx = blockIdx.x;
    const int n   = bx >> 7;                 // image
    const int rem = bx & 127;
    const int t6  = rem >> 1;                // tile
    const int fs  = rem & 1;                 // pair-split: pairs fs*8..fs*8+7
    const int ty = t6 >> 3, tx = t6 & 7;
    const int r0g = ty * 64 - 16;
    const int c0g = tx * 64 - 16;            // 16-aligned -> float4-aligned
    const int tid = threadIdx.x;
    const int P0 = fs * 8;

    const int lane = tid & 63;
    const int w    = tid >> 6;
    const int r4   = w & 3;                 // pass A N-tile / pass B M-tile
    const int half = w >> 2;                // splits mt (pass A) / nt (pass B)
    const int nn   = lane & 15;
    const int q8   = (lane >> 4) << 3;      // k-offset within K=32 fragment
    const int q4   = (lane >> 4) << 2;      // C/D row base within 16-tile
    const int cr   = r4 * 16 + nn;          // pass A: col c; pass B: row r
    const int u    = q8 - cr + 64;          // tap-phase for fragment tables
    const int b0   = r4 >> 1;               // first needed k-block (band skip)
    const int uoff = (u & 7) * 20 + (u >> 3);

    // ---- first-pair G/F loads issued first: latency hides under staging ----
    const int fa0 = ((P0 >> 2) << 3) + (P0 & 3);
    const uint4* fb0 = tabs + (size_t)fa0 * 800 + uoff;
    v8h Gre0[2], Gim0[2], Fre[2], Fim[2];
    #pragma unroll
    for (int j = 0; j < 2; ++j) {
        int idx = (b0 + j) * 4;
        Gre0[j] = ldfrag(fb0 + idx);
        Gim0[j] = ldfrag(fb0 + 160 + idx);
        Fre[j]  = ldfrag(fb0 + 320 + idx);
        Fim[j]  = ldfrag(fb0 + 480 + idx);
    }

    // ---- stage gray = 3-channel mean (f16), float4 loads, group bounds ----
    {
        const float* c0p = x + (size_t)n * 3 * IMG * IMG;
        const float* c1p = c0p + IMG * IMG;
        const float* c2p = c0p + 2 * IMG * IMG;
        for (int e = tid; e < 96 * 24; e += 512) {
            int hr = e / 24, g4 = e - hr * 24;
            int hc0 = g4 * 4;
            int gr = r0g + hr, gc0 = c0g + hc0;
            float4 v = make_float4(0.f, 0.f, 0.f, 0.f);
            if (hr < 95 && (unsigned)gr < IMG && (unsigned)gc0 < IMG) {
                size_t off = ((size_t)gr * IMG + gc0) >> 2;
                float4 a = ((const float4*)c0p)[off];
                float4 b = ((const float4*)c1p)[off];
                float4 c = ((const float4*)c2p)[off];
                v.x = (a.x + b.x + c.x) * (1.0f / 3.0f);
                v.y = (a.y + b.y + c.y) * (1.0f / 3.0f);
                v.z = (a.z + b.z + c.z) * (1.0f / 3.0f);
                v.w = (hc0 == 92) ? 0.0f : (a.w + b.w + c.w) * (1.0f / 3.0f);
            }
            uint2 w2;
            w2.x = pkrtz(v.x, v.y);
            w2.y = pkrtz(v.z, v.w);
            *(uint2*)(&gray[hr * GS + hc0]) = w2;
        }
    }
    __syncthreads();

    // ---- fused S0 (fs==0 only): 16x16 avg-pool of gray interior ----
    if (fs == 0 && tid < 256) {
        int cell = tid >> 4, sub = tid & 15;
        int pr = cell >> 2, pc = cell & 3;
        const _Float16* row = &gray[(16 + pr * 16 + sub) * GS + 16 + pc * 16];
        float s = 0.0f;
        #pragma unroll
        for (int j = 0; j < 16; ++j) s += (float)row[j];
        s += __shfl_xor(s, 1);
        s += __shfl_xor(s, 2);
        s += __shfl_xor(s, 4);
        s += __shfl_xor(s, 8);
        if (sub == 0)
            s0out[(size_t)n * 1024 + (ty * 4 + pr) * 32 + (tx * 4 + pc)] = s * (1.0f / 256.0f);
    }

    // ---- hoist filter-invariant gray A-fragments into registers ----
    v8h Agray[3][2];
    #pragma unroll
    for (int mi = 0; mi < 3; ++mi)
        #pragma unroll
        for (int j = 0; j < 2; ++j)
            Agray[mi][j] = *(const v8h*)(&gray[((half * 3 + mi) * 16 + nn) * GS + (b0 + j) * 32 + q8]);

    // gray is DEAD from here; its space is T buffer 0.  All gray reads
    // (S0 + hoist) must retire in every wave before T[0] writes: barrier.
    bar_lgkm();

    // ---- prologue: A(P0) -> T buffer 0 ----
    #pragma unroll
    for (int mi = 0; mi < 3; ++mi) {
        int mt = half * 3 + mi;
        v4f aR = {0.f, 0.f, 0.f, 0.f}, aI = {0.f, 0.f, 0.f, 0.f};
        #pragma unroll
        for (int j = 0; j < 2; ++j) {
            aR = __builtin_amdgcn_mfma_f32_16x16x32_f16(Agray[mi][j], Gre0[j], aR, 0, 0, 0);
            aI = __builtin_amdgcn_mfma_f32_16x16x32_f16(Agray[mi][j], Gim0[j], aI, 0, 0, 0);
        }
        int mb = mt * 16 + q4;
        uint2 pr, pi;
        pr.x = pkrtz(aR[0], aR[1]);  pr.y = pkrtz(aR[2], aR[3]);
        pi.x = pkrtz(aI[0], aI[1]);  pi.y = pkrtz(aI[2], aI[3]);
        // buffer for pair P0 (P0 even -> buffer 0): base U
        *(uint2*)(&U[cr * GS + mb]) = pr;
        *(uint2*)(&U[TBUF + cr * GS + mb]) = pi;
    }
    bar_lgkm();

    float* s1b = s1out + (size_t)n * NFILT * 1024;

    // ---- main loop over this block's 8 conjugate pairs, 1 barrier each ----
    for (int p = P0; p < P0 + 8; ++p) {
        // T base pointers computed arithmetically (no pointer-array init)
        _Float16* Trc = U + (size_t)(p & 1) * (2 * TBUF);
        _Float16* Tic = Trc + TBUF;
        _Float16* Trn = U + (size_t)((p + 1) & 1) * (2 * TBUF);
        _Float16* Tin = Trn + TBUF;
        const int fa  = ((p >> 2) << 3) + (p & 3);
        const int fbi = ((p >> 2) << 3) + 7 - (p & 3);
        const int nxp = (p < P0 + 7) ? p + 1 : p;
        const int nxfa = ((nxp >> 2) << 3) + (nxp & 3);
        const uint4* fbn = tabs + (size_t)nxfa * 800 + uoff;

        // ---- G(p+1) prefetch: issued early, consumed after pass B ----
        v8h Gre[2], Gim[2];
        #pragma unroll
        for (int j = 0; j < 2; ++j) {
            int idx = (b0 + j) * 4;
            Gre[j] = ldfrag(fbn + idx);
            Gim[j] = ldfrag(fbn + 160 + idx);
        }

        // ---- pass B: P1..P4 chains give BOTH filters of the pair ----
        #pragma unroll
        for (int ni = 0; ni < 2; ++ni) {
            int nt = half * 2 + ni;
            v4f P1 = {0.f, 0.f, 0.f, 0.f}, P2 = {0.f, 0.f, 0.f, 0.f};
            v4f P3 = {0.f, 0.f, 0.f, 0.f}, P4 = {0.f, 0.f, 0.f, 0.f};
            #pragma unroll
            for (int j = 0; j < 2; ++j) {
                v8h tR = *(const v8h*)(&Trc[(nt * 16 + nn) * GS + (b0 + j) * 32 + q8]);
                v8h tI = *(const v8h*)(&Tic[(nt * 16 + nn) * GS + (b0 + j) * 32 + q8]);
                P1 = __builtin_amdgcn_mfma_f32_16x16x32_f16(Fre[j], tR, P1, 0, 0, 0);
                P2 = __builtin_amdgcn_mfma_f32_16x16x32_f16(Fim[j], tI, P2, 0, 0, 0);
                P3 = __builtin_amdgcn_mfma_f32_16x16x32_f16(Fre[j], tI, P3, 0, 0, 0);
                P4 = __builtin_amdgcn_mfma_f32_16x16x32_f16(Fim[j], tR, P4, 0, 0, 0);
            }
            // fa = (P1-P2, P3+P4), fb = (P1+P2, P3-P4)
            v4f are = P1 - P2, aim = P3 + P4;
            v4f bre = P1 + P2, bim = P3 - P4;
            float sa0 = fsqrt(fmaf(are[0], are[0], fmaf(aim[0], aim[0], 1e-8f)));
            float sa1 = fsqrt(fmaf(are[1], are[1], fmaf(aim[1], aim[1], 1e-8f)));
            float sa2 = fsqrt(fmaf(are[2], are[2], fmaf(aim[2], aim[2], 1e-8f)));
            float sa3 = fsqrt(fmaf(are[3], are[3], fmaf(aim[3], aim[3], 1e-8f)));
            float sb0 = fsqrt(fmaf(bre[0], bre[0], fmaf(bim[0], bim[0], 1e-8f)));
            float sb1 = fsqrt(fmaf(bre[1], bre[1], fmaf(bim[1], bim[1], 1e-8f)));
            float sb2 = fsqrt(fmaf(bre[2], bre[2], fmaf(bim[2], bim[2], 1e-8f)));
            float sb3 = fsqrt(fmaf(bre[3], bre[3], fmaf(bim[3], bim[3], 1e-8f)));
            float ma = (sa0 + sa1) + (sa2 + sa3);
            float mb = (sb0 + sb1) + (sb2 + sb3);
            ma = dpp_add<0xB1>(ma);   mb = dpp_add<0xB1>(mb);   // quad_perm xor1
            ma = dpp_add<0x4E>(ma);   mb = dpp_add<0x4E>(mb);   // quad_perm xor2
            ma = dpp_add<0x141>(ma);  mb = dpp_add<0x141>(mb);  // row_half_mirror
            ma = dpp_add<0x140>(ma);  mb = dpp_add<0x140>(mb);  // row_mirror
            ma += __shfl_xor(ma, 16); mb += __shfl_xor(mb, 16);
            ma += __shfl_xor(ma, 32); mb += __shfl_xor(mb, 32);
            if (lane == 0) {
                s1b[((size_t)fa  * 32 + (ty * 4 + r4)) * 32 + (tx * 4 + nt)] = ma * (1.0f / 256.0f);
                s1b[((size_t)fbi * 32 + (ty * 4 + r4)) * 32 + (tx * 4 + nt)] = mb * (1.0f / 256.0f);
            }
        }

        // ---- pass A(p+1): gray . G -> T[(p+1)&1]; then F(p+1) loads ----
        if (p < P0 + 7) {
            #pragma unroll
            for (int mi = 0; mi < 3; ++mi) {
                int mt = half * 3 + mi;
                v4f aR = {0.f, 0.f, 0.f, 0.f}, aI = {0.f, 0.f, 0.f, 0.f};
                #pragma unroll
                for (int j = 0; j < 2; ++j) {
                    aR = __builtin_amdgcn_mfma_f32_16x16x32_f16(Agray[mi][j], Gre[j], aR, 0, 0, 0);
                    aI = __builtin_amdgcn_mfma_f32_16x16x32_f16(Agray[mi][j], Gim[j], aI, 0, 0, 0);
                }
                int mb = mt * 16 + q4;
                uint2 pr, pi;
                pr.x = pkrtz(aR[0], aR[1]);  pr.y = pkrtz(aR[2], aR[3]);
                pi.x = pkrtz(aI[0], aI[1]);  pi.y = pkrtz(aI[2], aI[3]);
                *(uint2*)(&Trn[cr * GS + mb]) = pr;
                *(uint2*)(&Tin[cr * GS + mb]) = pi;
            }
            // F(p+1) prefetch: latency spans the barrier into next iteration
            #pragma unroll
            for (int j = 0; j < 2; ++j) {
                int idx = (b0 + j) * 4;
                Fre[j] = ldfrag(fbn + 320 + idx);
                Fim[j] = ldfrag(fbn + 480 + idx);
            }
        }
        bar_lgkm();             // T ds ops drained; global loads in flight
    }
}

// ---------------------------------------------------------------------------
extern "C" void kernel_launch(void* const* d_in, const int* in_sizes, int n_in,
                              void* d_out, int out_size, void* d_ws, size_t ws_size,
                              hipStream_t stream) {
    const float* x = (const float*)d_in[0];
    float* out = (float*)d_out;
    unsigned* tabs = (unsigned*)d_ws;          // 102400 dwords = 400 KB scratch

    hipLaunchKernelGGL(make_tables, dim3(32), dim3(256), 0, stream, tabs);
    hipLaunchKernelGGL(conv_kernel, dim3(1024), dim3(512), 0, stream,
                       x, (const uint4*)tabs, out, out + 8192);
}

// Round 12
// 123.680 us; speedup vs baseline: 1.3901x; 1.3901x over previous
//
#include <hip/hip_runtime.h>
#include <math.h>

#define IMG   512
#define NFILT 32
#define PI_F  3.14159265358979323846f
#define GS    104      // LDS row stride in halves (208 B)
#define TBUF  (64 * GS)

typedef _Float16 v8h __attribute__((ext_vector_type(8)));
typedef float    v4f __attribute__((ext_vector_type(4)));

__device__ __forceinline__ unsigned pkrtz(float a, float b) {
    typedef __fp16 f16x2 __attribute__((ext_vector_type(2)));
    union { f16x2 h; unsigned u; } x;
    x.h = __builtin_amdgcn_cvt_pkrtz(a, b);
    return x.u;
}

template <int CTRL>
__device__ __forceinline__ float dpp_add(float v) {
    int t = __builtin_amdgcn_update_dpp(0, __float_as_int(v), CTRL, 0xf, 0xf, true);
    return v + __int_as_float(t);
}

#if __has_builtin(__builtin_amdgcn_sqrtf)
__device__ __forceinline__ float fsqrt(float x) { return __builtin_amdgcn_sqrtf(x); }
#else
__device__ __forceinline__ float fsqrt(float x) { return sqrtf(x); }
#endif

// Loop barrier: only LDS ops must drain; global prefetch loads stay in flight.
__device__ __forceinline__ void bar_lgkm() {
    asm volatile("s_waitcnt lgkmcnt(0)\n\ts_barrier" ::: "memory");
}

__device__ __forceinline__ v8h ldfrag(const uint4* p) {
    union { uint4 u; v8h h; } x; x.u = *p; return x.h;
}

// ---------------------------------------------------------------------------
// tabs layout (dwords): [filter:32][table:5][copy:8][block:20][dw:4]
//   tables: 0 g_re, 1 g_im, 2 f_re, 3 f_im, 4 -f_im
// ---------------------------------------------------------------------------
__global__ void make_tables(unsigned* __restrict__ tabs) {
    __shared__ _Float16 P[5][168];      // P[tbl][p] = tap(p-64), zero-padded
    const int fo = blockIdx.x;
    const int tid = threadIdx.x;
    for (int e = tid; e < 5 * 168; e += 256) ((_Float16*)P)[e] = (_Float16)0.0f;
    __syncthreads();
    if (tid < 160) {
        int tbl = tid >> 5, t = tid & 31;
        int s = (fo >> 3) + 1, o = fo & 7;
        float theta = (float)o * (PI_F / 7.0f);      // linspace(0, pi, 8)
        float sf = (float)s * 2.0f;                  // scale * SIGMA
        float kf = 2.0f * PI_F / ((float)s * sf);
        float a = kf * cosf(theta), b = kf * sinf(theta);
        float d = (float)(t - 16);
        float env = expf(-0.5f * d * d / (sf * sf));
        float v;
        switch (tbl) {
            case 0: v =  env * cosf(b * d); break;
            case 1: v =  env * sinf(b * d); break;
            case 2: v =  env * cosf(a * d); break;
            case 3: v =  env * sinf(a * d); break;
            default: v = -env * sinf(a * d); break;
        }
        P[tbl][t + 64] = (_Float16)v;
    }
    __syncthreads();
    unsigned* dst = tabs + (size_t)fo * 3200;
    for (int e = tid; e < 3200; e += 256) {
        int tbl  = e / 640;  int rem2 = e - tbl * 640;
        int copy = rem2 / 80; int idw = rem2 - copy * 80;
        int p0 = (idw >> 2) * 8 + copy + (idw & 3) * 2;   // = t0 + 64
        union { unsigned u; _Float16 h[2]; } p;
        p.h[0] = P[tbl][p0];
        p.h[1] = P[tbl][p0 + 1];
        dst[e] = p.u;
    }
}

// ---------------------------------------------------------------------------
// R20c (resubmit — R11 died at container acquisition, no kernel data; source
// differs from the R10-run R20b by ONLY the launch-bounds token).
// R10 post-mortem: (512,6) capped VGPR at 84 -> G/F register-prefetch spilled
// to scratch (WRITE_SIZE 2.1 -> 71.8 MB, VGPR_Count 40, 2x regression).
// Fix: (512,4) = 128-VGPR cap (this loop compiled to 52-64 VGPR there,
// no scratch, in R3-R5).  3 blocks/CU comes from LDS aliasing alone:
//   - fsplit=2: grid 1024 (8n x 64 tiles x 2), each block does 8 pairs
//   - gray LDS aliased with T buffers (gray dead after Agray hoist + S0):
//     LDS 53248 B < 160K/3 => 3 blocks/CU co-resident (24 waves, was 16)
//   - S1 stored direct to global; barrier between gray-readers & T[0] writes
// Hypothesis under test (R19 ruled out barriers/conflicts as the residual):
// R5's 55 us is latency under-hidden at 2 blocks/CU.
// ---------------------------------------------------------------------------
__launch_bounds__(512, 4)
__global__ void conv_kernel(const float* __restrict__ x,
                            const uint4* __restrict__ tabs,
                            float* __restrict__ s0out,
                            float* __restrict__ s1out) {
    // Union region: 4 T half-buffers of TBUF halves = 53248 B total.
    // Layout: [Tre0 | Tim0 | Tre1 | Tim1]; gray (96*GS) aliases Tre0+Tim0.
    __shared__ _Float16 U[4 * TBUF];
    _Float16* gray = U;

    const int bx = blockIdx.x;
    const int n   = bx >> 7;                 // image
    const int rem = bx & 127;
    const int t6  = rem >> 1;                // tile
    const int fs  = rem & 1;                 // pair-split: pairs fs*8..fs*8+7
    const int ty = t6 >> 3, tx = t6 & 7;
    const int r0g = ty * 64 - 16;
    const int c0g = tx * 64 - 16;            // 16-aligned -> float4-aligned
    const int tid = threadIdx.x;
    const int P0 = fs * 8;

    const int lane = tid & 63;
    const int w    = tid >> 6;
    const int r4   = w & 3;                 // pass A N-tile / pass B M-tile
    const int half = w >> 2;                // splits mt (pass A) / nt (pass B)
    const int nn   = lane & 15;
    const int q8   = (lane >> 4) << 3;      // k-offset within K=32 fragment
    const int q4   = (lane >> 4) << 2;      // C/D row base within 16-tile
    const int cr   = r4 * 16 + nn;          // pass A: col c; pass B: row r
    const int u    = q8 - cr + 64;          // tap-phase for fragment tables
    const int b0   = r4 >> 1;               // first needed k-block (band skip)
    const int uoff = (u & 7) * 20 + (u >> 3);

    // ---- first-pair G/F loads issued first: latency hides under staging ----
    const int fa0 = ((P0 >> 2) << 3) + (P0 & 3);
    const uint4* fb0 = tabs + (size_t)fa0 * 800 + uoff;
    v8h Gre0[2], Gim0[2], Fre[2], Fim[2];
    #pragma unroll
    for (int j = 0; j < 2; ++j) {
        int idx = (b0 + j) * 4;
        Gre0[j] = ldfrag(fb0 + idx);
        Gim0[j] = ldfrag(fb0 + 160 + idx);
        Fre[j]  = ldfrag(fb0 + 320 + idx);
        Fim[j]  = ldfrag(fb0 + 480 + idx);
    }

    // ---- stage gray = 3-channel mean (f16), float4 loads, group bounds ----
    {
        const float* c0p = x + (size_t)n * 3 * IMG * IMG;
        const float* c1p = c0p + IMG * IMG;
        const float* c2p = c0p + 2 * IMG * IMG;
        for (int e = tid; e < 96 * 24; e += 512) {
            int hr = e / 24, g4 = e - hr * 24;
            int hc0 = g4 * 4;
            int gr = r0g + hr, gc0 = c0g + hc0;
            float4 v = make_float4(0.f, 0.f, 0.f, 0.f);
            if (hr < 95 && (unsigned)gr < IMG && (unsigned)gc0 < IMG) {
                size_t off = ((size_t)gr * IMG + gc0) >> 2;
                float4 a = ((const float4*)c0p)[off];
                float4 b = ((const float4*)c1p)[off];
                float4 c = ((const float4*)c2p)[off];
                v.x = (a.x + b.x + c.x) * (1.0f / 3.0f);
                v.y = (a.y + b.y + c.y) * (1.0f / 3.0f);
                v.z = (a.z + b.z + c.z) * (1.0f / 3.0f);
                v.w = (hc0 == 92) ? 0.0f : (a.w + b.w + c.w) * (1.0f / 3.0f);
            }
            uint2 w2;
            w2.x = pkrtz(v.x, v.y);
            w2.y = pkrtz(v.z, v.w);
            *(uint2*)(&gray[hr * GS + hc0]) = w2;
        }
    }
    __syncthreads();

    // ---- fused S0 (fs==0 only): 16x16 avg-pool of gray interior ----
    if (fs == 0 && tid < 256) {
        int cell = tid >> 4, sub = tid & 15;
        int pr = cell >> 2, pc = cell & 3;
        const _Float16* row = &gray[(16 + pr * 16 + sub) * GS + 16 + pc * 16];
        float s = 0.0f;
        #pragma unroll
        for (int j = 0; j < 16; ++j) s += (float)row[j];
        s += __shfl_xor(s, 1);
        s += __shfl_xor(s, 2);
        s += __shfl_xor(s, 4);
        s += __shfl_xor(s, 8);
        if (sub == 0)
            s0out[(size_t)n * 1024 + (ty * 4 + pr) * 32 + (tx * 4 + pc)] = s * (1.0f / 256.0f);
    }

    // ---- hoist filter-invariant gray A-fragments into registers ----
    v8h Agray[3][2];
    #pragma unroll
    for (int mi = 0; mi < 3; ++mi)
        #pragma unroll
        for (int j = 0; j < 2; ++j)
            Agray[mi][j] = *(const v8h*)(&gray[((half * 3 + mi) * 16 + nn) * GS + (b0 + j) * 32 + q8]);

    // gray is DEAD from here; its space is T buffer 0.  All gray reads
    // (S0 + hoist) must retire in every wave before T[0] writes: barrier.
    bar_lgkm();

    // ---- prologue: A(P0) -> T buffer 0 ----
    #pragma unroll
    for (int mi = 0; mi < 3; ++mi) {
        int mt = half * 3 + mi;
        v4f aR = {0.f, 0.f, 0.f, 0.f}, aI = {0.f, 0.f, 0.f, 0.f};
        #pragma unroll
        for (int j = 0; j < 2; ++j) {
            aR = __builtin_amdgcn_mfma_f32_16x16x32_f16(Agray[mi][j], Gre0[j], aR, 0, 0, 0);
            aI = __builtin_amdgcn_mfma_f32_16x16x32_f16(Agray[mi][j], Gim0[j], aI, 0, 0, 0);
        }
        int mb = mt * 16 + q4;
        uint2 pr, pi;
        pr.x = pkrtz(aR[0], aR[1]);  pr.y = pkrtz(aR[2], aR[3]);
        pi.x = pkrtz(aI[0], aI[1]);  pi.y = pkrtz(aI[2], aI[3]);
        // buffer for pair P0 (P0 even -> buffer 0): base U
        *(uint2*)(&U[cr * GS + mb]) = pr;
        *(uint2*)(&U[TBUF + cr * GS + mb]) = pi;
    }
    bar_lgkm();

    float* s1b = s1out + (size_t)n * NFILT * 1024;

    // ---- main loop over this block's 8 conjugate pairs, 1 barrier each ----
    for (int p = P0; p < P0 + 8; ++p) {
        // T base pointers computed arithmetically (no pointer-array init:
        // gfx950 rejects addrspacecast static initializers — R9 lesson)
        _Float16* Trc = U + (size_t)(p & 1) * (2 * TBUF);
        _Float16* Tic = Trc + TBUF;
        _Float16* Trn = U + (size_t)((p + 1) & 1) * (2 * TBUF);
        _Float16* Tin = Trn + TBUF;
        const int fa  = ((p >> 2) << 3) + (p & 3);
        const int fbi = ((p >> 2) << 3) + 7 - (p & 3);
        const int nxp = (p < P0 + 7) ? p + 1 : p;
        const int nxfa = ((nxp >> 2) << 3) + (nxp & 3);
        const uint4* fbn = tabs + (size_t)nxfa * 800 + uoff;

        // ---- G(p+1) prefetch: issued early, consumed after pass B ----
        v8h Gre[2], Gim[2];
        #pragma unroll
        for (int j = 0; j < 2; ++j) {
            int idx = (b0 + j) * 4;
            Gre[j] = ldfrag(fbn + idx);
            Gim[j] = ldfrag(fbn + 160 + idx);
        }

        // ---- pass B: P1..P4 chains give BOTH filters of the pair ----
        #pragma unroll
        for (int ni = 0; ni < 2; ++ni) {
            int nt = half * 2 + ni;
            v4f P1 = {0.f, 0.f, 0.f, 0.f}, P2 = {0.f, 0.f, 0.f, 0.f};
            v4f P3 = {0.f, 0.f, 0.f, 0.f}, P4 = {0.f, 0.f, 0.f, 0.f};
            #pragma unroll
            for (int j = 0; j < 2; ++j) {
                v8h tR = *(const v8h*)(&Trc[(nt * 16 + nn) * GS + (b0 + j) * 32 + q8]);
                v8h tI = *(const v8h*)(&Tic[(nt * 16 + nn) * GS + (b0 + j) * 32 + q8]);
                P1 = __builtin_amdgcn_mfma_f32_16x16x32_f16(Fre[j], tR, P1, 0, 0, 0);
                P2 = __builtin_amdgcn_mfma_f32_16x16x32_f16(Fim[j], tI, P2, 0, 0, 0);
                P3 = __builtin_amdgcn_mfma_f32_16x16x32_f16(Fre[j], tI, P3, 0, 0, 0);
                P4 = __builtin_amdgcn_mfma_f32_16x16x32_f16(Fim[j], tR, P4, 0, 0, 0);
            }
            // fa = (P1-P2, P3+P4), fb = (P1+P2, P3-P4)
            v4f are = P1 - P2, aim = P3 + P4;
            v4f bre = P1 + P2, bim = P3 - P4;
            float sa0 = fsqrt(fmaf(are[0], are[0], fmaf(aim[0], aim[0], 1e-8f)));
            float sa1 = fsqrt(fmaf(are[1], are[1], fmaf(aim[1], aim[1], 1e-8f)));
            float sa2 = fsqrt(fmaf(are[2], are[2], fmaf(aim[2], aim[2], 1e-8f)));
            float sa3 = fsqrt(fmaf(are[3], are[3], fmaf(aim[3], aim[3], 1e-8f)));
            float sb0 = fsqrt(fmaf(bre[0], bre[0], fmaf(bim[0], bim[0], 1e-8f)));
            float sb1 = fsqrt(fmaf(bre[1], bre[1], fmaf(bim[1], bim[1], 1e-8f)));
            float sb2 = fsqrt(fmaf(bre[2], bre[2], fmaf(bim[2], bim[2], 1e-8f)));
            float sb3 = fsqrt(fmaf(bre[3], bre[3], fmaf(bim[3], bim[3], 1e-8f)));
            float ma = (sa0 + sa1) + (sa2 + sa3);
            float mb = (sb0 + sb1) + (sb2 + sb3);
            ma = dpp_add<0xB1>(ma);   mb = dpp_add<0xB1>(mb);   // quad_perm xor1
            ma = dpp_add<0x4E>(ma);   mb = dpp_add<0x4E>(mb);   // quad_perm xor2
            ma = dpp_add<0x141>(ma);  mb = dpp_add<0x141>(mb);  // row_half_mirror
            ma = dpp_add<0x140>(ma);  mb = dpp_add<0x140>(mb);  // row_mirror
            ma += __shfl_xor(ma, 16); mb += __shfl_xor(mb, 16);
            ma += __shfl_xor(ma, 32); mb += __shfl_xor(mb, 32);
            if (lane == 0) {
                s1b[((size_t)fa  * 32 + (ty * 4 + r4)) * 32 + (tx * 4 + nt)] = ma * (1.0f / 256.0f);
                s1b[((size_t)fbi * 32 + (ty * 4 + r4)) * 32 + (tx * 4 + nt)] = mb * (1.0f / 256.0f);
            }
        }

        // ---- pass A(p+1): gray . G -> T[(p+1)&1]; then F(p+1) loads ----
        if (p < P0 + 7) {
            #pragma unroll
            for (int mi = 0; mi < 3; ++mi) {
                int mt = half * 3 + mi;
                v4f aR = {0.f, 0.f, 0.f, 0.f}, aI = {0.f, 0.f, 0.f, 0.f};
                #pragma unroll
                for (int j = 0; j < 2; ++j) {
                    aR = __builtin_amdgcn_mfma_f32_16x16x32_f16(Agray[mi][j], Gre[j], aR, 0, 0, 0);
                    aI = __builtin_amdgcn_mfma_f32_16x16x32_f16(Agray[mi][j], Gim[j], aI, 0, 0, 0);
                }
                int mb = mt * 16 + q4;
                uint2 pr, pi;
                pr.x = pkrtz(aR[0], aR[1]);  pr.y = pkrtz(aR[2], aR[3]);
                pi.x = pkrtz(aI[0], aI[1]);  pi.y = pkrtz(aI[2], aI[3]);
                *(uint2*)(&Trn[cr * GS + mb]) = pr;
                *(uint2*)(&Tin[cr * GS + mb]) = pi;
            }
            // F(p+1) prefetch: latency spans the barrier into next iteration
            #pragma unroll
            for (int j = 0; j < 2; ++j) {
                int idx = (b0 + j) * 4;
                Fre[j] = ldfrag(fbn + 320 + idx);
                Fim[j] = ldfrag(fbn + 480 + idx);
            }
        }
        bar_lgkm();             // T ds ops drained; global loads in flight
    }
}

// ---------------------------------------------------------------------------
extern "C" void kernel_launch(void* const* d_in, const int* in_sizes, int n_in,
                              void* d_out, int out_size, void* d_ws, size_t ws_size,
                              hipStream_t stream) {
    const float* x = (const float*)d_in[0];
    float* out = (float*)d_out;
    unsigned* tabs = (unsigned*)d_ws;          // 102400 dwords = 400 KB scratch

    hipLaunchKernelGGL(make_tables, dim3(32), dim3(256), 0, stream, tabs);
    hipLaunchKernelGGL(conv_kernel, dim3(1024), dim3(512), 0, stream,
                       x, (const uint4*)tabs, out, out + 8192);
}

// Round 13
// 118.274 us; speedup vs baseline: 1.4537x; 1.0457x over previous
//
#include <hip/hip_runtime.h>
#include <math.h>

#define IMG   512
#define NFILT 32
#define NPAIR 16
#define PI_F  3.14159265358979323846f
#define GS    104      // LDS row stride in halves (208 B)

typedef _Float16 v8h __attribute__((ext_vector_type(8)));
typedef float    v4f __attribute__((ext_vector_type(4)));

__device__ __forceinline__ unsigned pkrtz(float a, float b) {
    typedef __fp16 f16x2 __attribute__((ext_vector_type(2)));
    union { f16x2 h; unsigned u; } x;
    x.h = __builtin_amdgcn_cvt_pkrtz(a, b);
    return x.u;
}

template <int CTRL>
__device__ __forceinline__ float dpp_add(float v) {
    int t = __builtin_amdgcn_update_dpp(0, __float_as_int(v), CTRL, 0xf, 0xf, true);
    return v + __int_as_float(t);
}

#if __has_builtin(__builtin_amdgcn_sqrtf)
__device__ __forceinline__ float fsqrt(float x) { return __builtin_amdgcn_sqrtf(x); }
#else
__device__ __forceinline__ float fsqrt(float x) { return sqrtf(x); }
#endif

// Loop barrier: only LDS ops must drain; global prefetch loads stay in flight.
__device__ __forceinline__ void bar_lgkm() {
    asm volatile("s_waitcnt lgkmcnt(0)\n\ts_barrier" ::: "memory");
}

__device__ __forceinline__ v8h ldfrag(const uint4* p) {
    union { uint4 u; v8h h; } x; x.u = *p; return x.h;
}

// ---------------------------------------------------------------------------
// tabs layout (dwords): [filter:32][table:5][copy:8][block:20][dw:4]
//   tables: 0 g_re, 1 g_im, 2 f_re, 3 f_im, 4 -f_im
// ---------------------------------------------------------------------------
__global__ void make_tables(unsigned* __restrict__ tabs) {
    __shared__ _Float16 P[5][168];      // P[tbl][p] = tap(p-64), zero-padded
    const int fo = blockIdx.x;
    const int tid = threadIdx.x;
    for (int e = tid; e < 5 * 168; e += 256) ((_Float16*)P)[e] = (_Float16)0.0f;
    __syncthreads();
    if (tid < 160) {
        int tbl = tid >> 5, t = tid & 31;
        int s = (fo >> 3) + 1, o = fo & 7;
        float theta = (float)o * (PI_F / 7.0f);      // linspace(0, pi, 8)
        float sf = (float)s * 2.0f;                  // scale * SIGMA
        float kf = 2.0f * PI_F / ((float)s * sf);
        float a = kf * cosf(theta), b = kf * sinf(theta);
        float d = (float)(t - 16);
        float env = expf(-0.5f * d * d / (sf * sf));
        float v;
        switch (tbl) {
            case 0: v =  env * cosf(b * d); break;
            case 1: v =  env * sinf(b * d); break;
            case 2: v =  env * cosf(a * d); break;
            case 3: v =  env * sinf(a * d); break;
            default: v = -env * sinf(a * d); break;
        }
        P[tbl][t + 64] = (_Float16)v;
    }
    __syncthreads();
    unsigned* dst = tabs + (size_t)fo * 3200;
    for (int e = tid; e < 3200; e += 256) {
        int tbl  = e / 640;  int rem2 = e - tbl * 640;
        int copy = rem2 / 80; int idw = rem2 - copy * 80;
        int p0 = (idw >> 2) * 8 + copy + (idw & 3) * 2;   // = t0 + 64
        union { unsigned u; _Float16 h[2]; } p;
        p.h[0] = P[tbl][p0];
        p.h[1] = P[tbl][p0 + 1];
        dst[e] = p.u;
    }
}

// ---------------------------------------------------------------------------
// R21 = R3 base (best measured: 54.2 us) + two WORK cuts.
// Model from 13 measurements: wall ~= sum of pipe busies (VALU 23 + LDS 15-20
// + MFMA 12 + trans 5 ~= 55); scheduling changes null, work changes move time
// proportionally.  So: cut work.
//  1. T-granule XOR swizzle (G' = G ^ (row&3), both sides; reads get it free
//     via hx8) — targets the 3.81M SQ_LDS_BANK_CONFLICT cycles that track T
//     traffic exactly (R1 7.48M -> R2 3.81M -> R19-no-T 0.17M).
//  2. Packed s/t magnitude: |za|^2 = s-2t, |zb|^2 = s+2t, s = sum Pi^2 + eps,
//     t = P1P2 - P3P4, as v4f exprs (v_pk_fma_f32).  fmaxf clamp before sqrt
//     (fma rounding can make s-2t slightly negative when |z| ~ 0).
// ---------------------------------------------------------------------------
__launch_bounds__(512, 4)
__global__ void conv_kernel(const float* __restrict__ x,
                            const uint4* __restrict__ tabs,
                            float* __restrict__ s0out,
                            float* __restrict__ s1out) {
    __shared__ _Float16 gray[96 * GS];       // 19968 B
    __shared__ _Float16 Tre[2][64 * GS];     // 2 x 13312 B  (T^T: [col c][row m])
    __shared__ _Float16 Tim[2][64 * GS];     // 2 x 13312 B
    __shared__ float    s1st[NFILT * 16];    // 2048 B, staged pooled outputs

    const int bx = blockIdx.x;
    const int n  = bx >> 6;                  // image
    const int t6 = bx & 63;                  // tile
    const int ty = t6 >> 3, tx = t6 & 7;
    const int r0g = ty * 64 - 16;
    const int c0g = tx * 64 - 16;            // 16-aligned -> float4-aligned
    const int tid = threadIdx.x;

    const int lane = tid & 63;
    const int w    = tid >> 6;
    const int r4   = w & 3;                 // pass A N-tile / pass B M-tile
    const int half = w >> 2;                // splits mt (pass A) / nt (pass B)
    const int nn   = lane & 15;
    const int q8   = (lane >> 4) << 3;      // k-offset within K=32 fragment
    const int q4   = (lane >> 4) << 2;      // C/D row base within 16-tile
    const int cr   = r4 * 16 + nn;          // pass A: col c; pass B: row r
    const int u    = q8 - cr + 64;          // tap-phase for fragment tables
    const int b0   = r4 >> 1;               // first needed k-block (band skip)
    const int uoff = (u & 7) * 20 + (u >> 3);
    // swizzled 16B-granule offsets:
    //   read:  granule (4(b0+j) + lane>>4) ^ (row&3); row&3 = nn&3 ->
    //          halves offset = (b0+j)*32 + hx8  (hx8 replaces q8, same cost)
    //   write: granule ((mt<<1)|(q4>>3)) ^ (cr&3), byte-half q4&7
    const int hx8  = (((lane >> 4) ^ (nn & 3)) << 3);
    const int crx3 = cr & 3;

    // ---- filter-0 G/F loads issued first: latency hides under staging ----
    const uint4* fb0 = tabs + uoff;
    v8h Gre0[2], Gim0[2], Fre[2], Fim[2];
    #pragma unroll
    for (int j = 0; j < 2; ++j) {
        int idx = (b0 + j) * 4;
        Gre0[j] = ldfrag(fb0 + idx);
        Gim0[j] = ldfrag(fb0 + 160 + idx);
        Fre[j]  = ldfrag(fb0 + 320 + idx);
        Fim[j]  = ldfrag(fb0 + 480 + idx);
    }

    // ---- stage gray = 3-channel mean (f16), float4 loads, group bounds ----
    {
        const float* c0p = x + (size_t)n * 3 * IMG * IMG;
        const float* c1p = c0p + IMG * IMG;
        const float* c2p = c0p + 2 * IMG * IMG;
        for (int e = tid; e < 96 * 24; e += 512) {
            int hr = e / 24, g4 = e - hr * 24;
            int hc0 = g4 * 4;
            int gr = r0g + hr, gc0 = c0g + hc0;
            float4 v = make_float4(0.f, 0.f, 0.f, 0.f);
            if (hr < 95 && (unsigned)gr < IMG && (unsigned)gc0 < IMG) {
                size_t off = ((size_t)gr * IMG + gc0) >> 2;
                float4 a = ((const float4*)c0p)[off];
                float4 b = ((const float4*)c1p)[off];
                float4 c = ((const float4*)c2p)[off];
                v.x = (a.x + b.x + c.x) * (1.0f / 3.0f);
                v.y = (a.y + b.y + c.y) * (1.0f / 3.0f);
                v.z = (a.z + b.z + c.z) * (1.0f / 3.0f);
                v.w = (hc0 == 92) ? 0.0f : (a.w + b.w + c.w) * (1.0f / 3.0f);
            }
            uint2 w2;
            w2.x = pkrtz(v.x, v.y);
            w2.y = pkrtz(v.z, v.w);
            *(uint2*)(&gray[hr * GS + hc0]) = w2;
        }
    }
    __syncthreads();

    // ---- fused S0: 16x16 avg-pool of gray interior ----
    if (tid < 256) {
        int cell = tid >> 4, sub = tid & 15;
        int pr = cell >> 2, pc = cell & 3;
        const _Float16* row = &gray[(16 + pr * 16 + sub) * GS + 16 + pc * 16];
        float s = 0.0f;
        #pragma unroll
        for (int j = 0; j < 16; ++j) s += (float)row[j];
        s += __shfl_xor(s, 1);
        s += __shfl_xor(s, 2);
        s += __shfl_xor(s, 4);
        s += __shfl_xor(s, 8);
        if (sub == 0)
            s0out[(size_t)n * 1024 + (ty * 4 + pr) * 32 + (tx * 4 + pc)] = s * (1.0f / 256.0f);
    }

    // ---- hoist filter-invariant gray A-fragments into registers ----
    v8h Agray[3][2];
    #pragma unroll
    for (int mi = 0; mi < 3; ++mi)
        #pragma unroll
        for (int j = 0; j < 2; ++j)
            Agray[mi][j] = *(const v8h*)(&gray[((half * 3 + mi) * 16 + nn) * GS + (b0 + j) * 32 + q8]);

    // ---- prologue: A(pair 0) -> T[0], swizzled writes ----
    #pragma unroll
    for (int mi = 0; mi < 3; ++mi) {
        int mt = half * 3 + mi;
        v4f aR = {0.f, 0.f, 0.f, 0.f}, aI = {0.f, 0.f, 0.f, 0.f};
        #pragma unroll
        for (int j = 0; j < 2; ++j) {
            aR = __builtin_amdgcn_mfma_f32_16x16x32_f16(Agray[mi][j], Gre0[j], aR, 0, 0, 0);
            aI = __builtin_amdgcn_mfma_f32_16x16x32_f16(Agray[mi][j], Gim0[j], aI, 0, 0, 0);
        }
        int gw = (((mt << 1) | (q4 >> 3)) ^ crx3);
        int wo = cr * GS + gw * 8 + (q4 & 7);
        uint2 pr, pi;
        pr.x = pkrtz(aR[0], aR[1]);  pr.y = pkrtz(aR[2], aR[3]);
        pi.x = pkrtz(aI[0], aI[1]);  pi.y = pkrtz(aI[2], aI[3]);
        *(uint2*)(&Tre[0][wo]) = pr;
        *(uint2*)(&Tim[0][wo]) = pi;
    }
    __syncthreads();

    // ---- main loop over 16 conjugate pairs, one lgkm-barrier each ----
    for (int p = 0; p < NPAIR; ++p) {
        const _Float16* Tr  = Tre[p & 1];
        const _Float16* Ti  = Tim[p & 1];
        _Float16*       Trn = Tre[(p + 1) & 1];
        _Float16*       Tin = Tim[(p + 1) & 1];
        const int fa  = ((p >> 2) << 3) + (p & 3);
        const int fbi = ((p >> 2) << 3) + 7 - (p & 3);
        const int nxp = (p < NPAIR - 1) ? p + 1 : p;
        const int nxfa = ((nxp >> 2) << 3) + (nxp & 3);
        const uint4* fbn = tabs + (size_t)nxfa * 800 + uoff;

        // ---- G(p+1) prefetch: issued early, consumed after pass B ----
        v8h Gre[2], Gim[2];
        #pragma unroll
        for (int j = 0; j < 2; ++j) {
            int idx = (b0 + j) * 4;
            Gre[j] = ldfrag(fbn + idx);
            Gim[j] = ldfrag(fbn + 160 + idx);
        }

        // ---- pass B: P1..P4 chains give BOTH filters of the pair ----
        #pragma unroll
        for (int ni = 0; ni < 2; ++ni) {
            int nt = half * 2 + ni;
            v4f P1 = {0.f, 0.f, 0.f, 0.f}, P2 = {0.f, 0.f, 0.f, 0.f};
            v4f P3 = {0.f, 0.f, 0.f, 0.f}, P4 = {0.f, 0.f, 0.f, 0.f};
            #pragma unroll
            for (int j = 0; j < 2; ++j) {
                int ro = (nt * 16 + nn) * GS + (b0 + j) * 32 + hx8;   // swizzled
                v8h tR = *(const v8h*)(&Tr[ro]);
                v8h tI = *(const v8h*)(&Ti[ro]);
                P1 = __builtin_amdgcn_mfma_f32_16x16x32_f16(Fre[j], tR, P1, 0, 0, 0);
                P2 = __builtin_amdgcn_mfma_f32_16x16x32_f16(Fim[j], tI, P2, 0, 0, 0);
                P3 = __builtin_amdgcn_mfma_f32_16x16x32_f16(Fre[j], tI, P3, 0, 0, 0);
                P4 = __builtin_amdgcn_mfma_f32_16x16x32_f16(Fim[j], tR, P4, 0, 0, 0);
            }
            // |za|^2 = s - 2t, |zb|^2 = s + 2t  (packed f32 ops)
            const v4f eps4 = {1e-8f, 1e-8f, 1e-8f, 1e-8f};
            v4f s4 = P1 * P1 + eps4;
            s4 = P2 * P2 + s4;
            s4 = P3 * P3 + s4;
            s4 = P4 * P4 + s4;
            v4f t4 = P1 * P2 - P3 * P4;
            t4 = t4 + t4;
            v4f na = s4 - t4, nb = s4 + t4;
            float sa0 = fsqrt(fmaxf(na[0], 1e-8f));
            float sa1 = fsqrt(fmaxf(na[1], 1e-8f));
            float sa2 = fsqrt(fmaxf(na[2], 1e-8f));
            float sa3 = fsqrt(fmaxf(na[3], 1e-8f));
            float sb0 = fsqrt(fmaxf(nb[0], 1e-8f));
            float sb1 = fsqrt(fmaxf(nb[1], 1e-8f));
            float sb2 = fsqrt(fmaxf(nb[2], 1e-8f));
            float sb3 = fsqrt(fmaxf(nb[3], 1e-8f));
            float ma = (sa0 + sa1) + (sa2 + sa3);
            float mb = (sb0 + sb1) + (sb2 + sb3);
            ma = dpp_add<0xB1>(ma);   mb = dpp_add<0xB1>(mb);   // quad_perm xor1
            ma = dpp_add<0x4E>(ma);   mb = dpp_add<0x4E>(mb);   // quad_perm xor2
            ma = dpp_add<0x141>(ma);  mb = dpp_add<0x141>(mb);  // row_half_mirror
            ma = dpp_add<0x140>(ma);  mb = dpp_add<0x140>(mb);  // row_mirror
            ma += __shfl_xor(ma, 16); mb += __shfl_xor(mb, 16);
            ma += __shfl_xor(ma, 32); mb += __shfl_xor(mb, 32);
            if (lane == 0) {
                s1st[fa  * 16 + r4 * 4 + nt] = ma;
                s1st[fbi * 16 + r4 * 4 + nt] = mb;
            }
        }

        // ---- pass A(p+1): gray . G -> T[(p+1)&1], swizzled; F(p+1) loads ----
        if (p < NPAIR - 1) {
            #pragma unroll
            for (int mi = 0; mi < 3; ++mi) {
                int mt = half * 3 + mi;
                v4f aR = {0.f, 0.f, 0.f, 0.f}, aI = {0.f, 0.f, 0.f, 0.f};
                #pragma unroll
                for (int j = 0; j < 2; ++j) {
                    aR = __builtin_amdgcn_mfma_f32_16x16x32_f16(Agray[mi][j], Gre[j], aR, 0, 0, 0);
                    aI = __builtin_amdgcn_mfma_f32_16x16x32_f16(Agray[mi][j], Gim[j], aI, 0, 0, 0);
                }
                int gw = (((mt << 1) | (q4 >> 3)) ^ crx3);
                int wo = cr * GS + gw * 8 + (q4 & 7);
                uint2 pr, pi;
                pr.x = pkrtz(aR[0], aR[1]);  pr.y = pkrtz(aR[2], aR[3]);
                pi.x = pkrtz(aI[0], aI[1]);  pi.y = pkrtz(aI[2], aI[3]);
                *(uint2*)(&Trn[wo]) = pr;
                *(uint2*)(&Tin[wo]) = pi;
            }
            // F(p+1) prefetch: latency spans the lgkm-barrier
            #pragma unroll
            for (int j = 0; j < 2; ++j) {
                int idx = (b0 + j) * 4;
                Fre[j] = ldfrag(fbn + 320 + idx);
                Fim[j] = ldfrag(fbn + 480 + idx);
            }
        }
        bar_lgkm();             // T ds ops drained; global loads in flight
    }

    // ---- epilogue: flush staged S1 (loop ended with a barrier) ----
    float* s1b = s1out + (size_t)n * NFILT * 32 * 32;
    for (int e = tid; e < NFILT * 16; e += 512) {
        int fi = e >> 4, cell = e & 15;
        int r4c = cell >> 2, ntc = cell & 3;
        s1b[((size_t)fi * 32 + (ty * 4 + r4c)) * 32 + (tx * 4 + ntc)] =
            s1st[e] * (1.0f / 256.0f);
    }
}

// ---------------------------------------------------------------------------
extern "C" void kernel_launch(void* const* d_in, const int* in_sizes, int n_in,
                              void* d_out, int out_size, void* d_ws, size_t ws_size,
                              hipStream_t stream) {
    const float* x = (const float*)d_in[0];
    float* out = (float*)d_out;
    unsigned* tabs = (unsigned*)d_ws;          // 102400 dwords = 400 KB scratch

    hipLaunchKernelGGL(make_tables, dim3(32), dim3(256), 0, stream, tabs);
    hipLaunchKernelGGL(conv_kernel, dim3(512), dim3(512), 0, stream,
                       x, (const uint4*)tabs, out, out + 8192);
}

// Round 14
// 114.106 us; speedup vs baseline: 1.5068x; 1.0365x over previous
//
#include <hip/hip_runtime.h>
#include <math.h>

#define IMG   512
#define NFILT 32
#define NPAIR 16
#define PI_F  3.14159265358979323846f
#define GS    104      // LDS row stride in halves (208 B) — tuned layout, do not perturb (R13 lesson)

typedef _Float16 v8h __attribute__((ext_vector_type(8)));
typedef float    v4f __attribute__((ext_vector_type(4)));

__device__ __forceinline__ unsigned pkrtz(float a, float b) {
    typedef __fp16 f16x2 __attribute__((ext_vector_type(2)));
    union { f16x2 h; unsigned u; } x;
    x.h = __builtin_amdgcn_cvt_pkrtz(a, b);
    return x.u;
}

template <int CTRL>
__device__ __forceinline__ float dpp_add(float v) {
    int t = __builtin_amdgcn_update_dpp(0, __float_as_int(v), CTRL, 0xf, 0xf, true);
    return v + __int_as_float(t);
}

#if __has_builtin(__builtin_amdgcn_sqrtf)
__device__ __forceinline__ float fsqrt(float x) { return __builtin_amdgcn_sqrtf(x); }
#else
__device__ __forceinline__ float fsqrt(float x) { return sqrtf(x); }
#endif

// Loop barrier: only LDS ops must drain; global prefetch loads stay in flight.
__device__ __forceinline__ void bar_lgkm() {
    asm volatile("s_waitcnt lgkmcnt(0)\n\ts_barrier" ::: "memory");
}

__device__ __forceinline__ v8h ldfrag(const uint4* p) {
    union { uint4 u; v8h h; } x; x.u = *p; return x.h;
}

// ---------------------------------------------------------------------------
// tabs layout (dwords): [filter:32][table:5][copy:8][block:20][dw:4]
//   tables: 0 g_re, 1 g_im, 2 f_re, 3 f_im, 4 -f_im
// ---------------------------------------------------------------------------
__global__ void make_tables(unsigned* __restrict__ tabs) {
    __shared__ _Float16 P[5][168];      // P[tbl][p] = tap(p-64), zero-padded
    const int fo = blockIdx.x;
    const int tid = threadIdx.x;
    for (int e = tid; e < 5 * 168; e += 256) ((_Float16*)P)[e] = (_Float16)0.0f;
    __syncthreads();
    if (tid < 160) {
        int tbl = tid >> 5, t = tid & 31;
        int s = (fo >> 3) + 1, o = fo & 7;
        float theta = (float)o * (PI_F / 7.0f);      // linspace(0, pi, 8)
        float sf = (float)s * 2.0f;                  // scale * SIGMA
        float kf = 2.0f * PI_F / ((float)s * sf);
        float a = kf * cosf(theta), b = kf * sinf(theta);
        float d = (float)(t - 16);
        float env = expf(-0.5f * d * d / (sf * sf));
        float v;
        switch (tbl) {
            case 0: v =  env * cosf(b * d); break;
            case 1: v =  env * sinf(b * d); break;
            case 2: v =  env * cosf(a * d); break;
            case 3: v =  env * sinf(a * d); break;
            default: v = -env * sinf(a * d); break;
        }
        P[tbl][t + 64] = (_Float16)v;
    }
    __syncthreads();
    unsigned* dst = tabs + (size_t)fo * 3200;
    for (int e = tid; e < 3200; e += 256) {
        int tbl  = e / 640;  int rem2 = e - tbl * 640;
        int copy = rem2 / 80; int idw = rem2 - copy * 80;
        int p0 = (idw >> 2) * 8 + copy + (idw & 3) * 2;   // = t0 + 64
        union { unsigned u; _Float16 h[2]; } p;
        p.h[0] = P[tbl][p0];
        p.h[1] = P[tbl][p0 + 1];
        dst[e] = p.u;
    }
}

// ---------------------------------------------------------------------------
// R22 = R3 base (best: 54.2 us) + verified work cuts only.
// R13 A/B results: granule swizzle REGRESSED (conflicts 3.81M -> 11.15M;
// GS=104 was already the tuned layout) -> reverted.  Packed s/t magnitude
// VERIFIED (-VALU, absmax unchanged) -> kept.  New cut: the shfl_xor(16/32)
// reduction tails are ds_bpermute = full-wave LDS-pipe ops (8/wave-pair);
// replace with per-16-group partial writes (lane&15==0, 4 active lanes) to
// s1st4[out][grp] and a 4-way sum in the epilogue.  LDS 81408 B -> still
// 2 blocks/CU (162816 <= 163840).
// ---------------------------------------------------------------------------
__launch_bounds__(512, 4)
__global__ void conv_kernel(const float* __restrict__ x,
                            const uint4* __restrict__ tabs,
                            float* __restrict__ s0out,
                            float* __restrict__ s1out) {
    __shared__ _Float16 gray[96 * GS];        // 19968 B
    __shared__ _Float16 Tre[2][64 * GS];      // 2 x 13312 B  (T^T: [col c][row m])
    __shared__ _Float16 Tim[2][64 * GS];      // 2 x 13312 B
    __shared__ float    s1st4[NFILT * 16 * 4]; // 8192 B: [filter][cell][group]

    const int bx = blockIdx.x;
    const int n  = bx >> 6;                  // image
    const int t6 = bx & 63;                  // tile
    const int ty = t6 >> 3, tx = t6 & 7;
    const int r0g = ty * 64 - 16;
    const int c0g = tx * 64 - 16;            // 16-aligned -> float4-aligned
    const int tid = threadIdx.x;

    const int lane = tid & 63;
    const int w    = tid >> 6;
    const int r4   = w & 3;                 // pass A N-tile / pass B M-tile
    const int half = w >> 2;                // splits mt (pass A) / nt (pass B)
    const int nn   = lane & 15;
    const int q8   = (lane >> 4) << 3;      // k-offset within K=32 fragment
    const int q4   = (lane >> 4) << 2;      // C/D row base within 16-tile
    const int cr   = r4 * 16 + nn;          // pass A: col c; pass B: row r
    const int u    = q8 - cr + 64;          // tap-phase for fragment tables
    const int b0   = r4 >> 1;               // first needed k-block (band skip)
    const int uoff = (u & 7) * 20 + (u >> 3);
    const int grp  = lane >> 4;             // 16-lane reduction group

    // ---- filter-0 G/F loads issued first: latency hides under staging ----
    const uint4* fb0 = tabs + uoff;
    v8h Gre0[2], Gim0[2], Fre[2], Fim[2];
    #pragma unroll
    for (int j = 0; j < 2; ++j) {
        int idx = (b0 + j) * 4;
        Gre0[j] = ldfrag(fb0 + idx);
        Gim0[j] = ldfrag(fb0 + 160 + idx);
        Fre[j]  = ldfrag(fb0 + 320 + idx);
        Fim[j]  = ldfrag(fb0 + 480 + idx);
    }

    // ---- stage gray = 3-channel mean (f16), float4 loads, group bounds ----
    {
        const float* c0p = x + (size_t)n * 3 * IMG * IMG;
        const float* c1p = c0p + IMG * IMG;
        const float* c2p = c0p + 2 * IMG * IMG;
        for (int e = tid; e < 96 * 24; e += 512) {
            int hr = e / 24, g4 = e - hr * 24;
            int hc0 = g4 * 4;
            int gr = r0g + hr, gc0 = c0g + hc0;
            float4 v = make_float4(0.f, 0.f, 0.f, 0.f);
            if (hr < 95 && (unsigned)gr < IMG && (unsigned)gc0 < IMG) {
                size_t off = ((size_t)gr * IMG + gc0) >> 2;
                float4 a = ((const float4*)c0p)[off];
                float4 b = ((const float4*)c1p)[off];
                float4 c = ((const float4*)c2p)[off];
                v.x = (a.x + b.x + c.x) * (1.0f / 3.0f);
                v.y = (a.y + b.y + c.y) * (1.0f / 3.0f);
                v.z = (a.z + b.z + c.z) * (1.0f / 3.0f);
                v.w = (hc0 == 92) ? 0.0f : (a.w + b.w + c.w) * (1.0f / 3.0f);
            }
            uint2 w2;
            w2.x = pkrtz(v.x, v.y);
            w2.y = pkrtz(v.z, v.w);
            *(uint2*)(&gray[hr * GS + hc0]) = w2;
        }
    }
    __syncthreads();

    // ---- fused S0: 16x16 avg-pool of gray interior ----
    if (tid < 256) {
        int cell = tid >> 4, sub = tid & 15;
        int pr = cell >> 2, pc = cell & 3;
        const _Float16* row = &gray[(16 + pr * 16 + sub) * GS + 16 + pc * 16];
        float s = 0.0f;
        #pragma unroll
        for (int j = 0; j < 16; ++j) s += (float)row[j];
        s += __shfl_xor(s, 1);
        s += __shfl_xor(s, 2);
        s += __shfl_xor(s, 4);
        s += __shfl_xor(s, 8);
        if (sub == 0)
            s0out[(size_t)n * 1024 + (ty * 4 + pr) * 32 + (tx * 4 + pc)] = s * (1.0f / 256.0f);
    }

    // ---- hoist filter-invariant gray A-fragments into registers ----
    v8h Agray[3][2];
    #pragma unroll
    for (int mi = 0; mi < 3; ++mi)
        #pragma unroll
        for (int j = 0; j < 2; ++j)
            Agray[mi][j] = *(const v8h*)(&gray[((half * 3 + mi) * 16 + nn) * GS + (b0 + j) * 32 + q8]);

    // ---- prologue: A(pair 0) -> T[0] ----
    #pragma unroll
    for (int mi = 0; mi < 3; ++mi) {
        int mt = half * 3 + mi;
        v4f aR = {0.f, 0.f, 0.f, 0.f}, aI = {0.f, 0.f, 0.f, 0.f};
        #pragma unroll
        for (int j = 0; j < 2; ++j) {
            aR = __builtin_amdgcn_mfma_f32_16x16x32_f16(Agray[mi][j], Gre0[j], aR, 0, 0, 0);
            aI = __builtin_amdgcn_mfma_f32_16x16x32_f16(Agray[mi][j], Gim0[j], aI, 0, 0, 0);
        }
        int mb = mt * 16 + q4;
        uint2 pr, pi;
        pr.x = pkrtz(aR[0], aR[1]);  pr.y = pkrtz(aR[2], aR[3]);
        pi.x = pkrtz(aI[0], aI[1]);  pi.y = pkrtz(aI[2], aI[3]);
        *(uint2*)(&Tre[0][cr * GS + mb]) = pr;
        *(uint2*)(&Tim[0][cr * GS + mb]) = pi;
    }
    __syncthreads();

    // ---- main loop over 16 conjugate pairs, one lgkm-barrier each ----
    for (int p = 0; p < NPAIR; ++p) {
        const _Float16* Tr  = Tre[p & 1];
        const _Float16* Ti  = Tim[p & 1];
        _Float16*       Trn = Tre[(p + 1) & 1];
        _Float16*       Tin = Tim[(p + 1) & 1];
        const int fa  = ((p >> 2) << 3) + (p & 3);
        const int fbi = ((p >> 2) << 3) + 7 - (p & 3);
        const int nxp = (p < NPAIR - 1) ? p + 1 : p;
        const int nxfa = ((nxp >> 2) << 3) + (nxp & 3);
        const uint4* fbn = tabs + (size_t)nxfa * 800 + uoff;

        // ---- G(p+1) prefetch: issued early, consumed after pass B ----
        v8h Gre[2], Gim[2];
        #pragma unroll
        for (int j = 0; j < 2; ++j) {
            int idx = (b0 + j) * 4;
            Gre[j] = ldfrag(fbn + idx);
            Gim[j] = ldfrag(fbn + 160 + idx);
        }

        // ---- pass B: P1..P4 chains give BOTH filters of the pair ----
        #pragma unroll
        for (int ni = 0; ni < 2; ++ni) {
            int nt = half * 2 + ni;
            v4f P1 = {0.f, 0.f, 0.f, 0.f}, P2 = {0.f, 0.f, 0.f, 0.f};
            v4f P3 = {0.f, 0.f, 0.f, 0.f}, P4 = {0.f, 0.f, 0.f, 0.f};
            #pragma unroll
            for (int j = 0; j < 2; ++j) {
                int ro = (nt * 16 + nn) * GS + (b0 + j) * 32 + q8;
                v8h tR = *(const v8h*)(&Tr[ro]);
                v8h tI = *(const v8h*)(&Ti[ro]);
                P1 = __builtin_amdgcn_mfma_f32_16x16x32_f16(Fre[j], tR, P1, 0, 0, 0);
                P2 = __builtin_amdgcn_mfma_f32_16x16x32_f16(Fim[j], tI, P2, 0, 0, 0);
                P3 = __builtin_amdgcn_mfma_f32_16x16x32_f16(Fre[j], tI, P3, 0, 0, 0);
                P4 = __builtin_amdgcn_mfma_f32_16x16x32_f16(Fim[j], tR, P4, 0, 0, 0);
            }
            // |za|^2 = s - 2t, |zb|^2 = s + 2t (packed f32; verified R21)
            const v4f eps4 = {1e-8f, 1e-8f, 1e-8f, 1e-8f};
            v4f s4 = P1 * P1 + eps4;
            s4 = P2 * P2 + s4;
            s4 = P3 * P3 + s4;
            s4 = P4 * P4 + s4;
            v4f t4 = P1 * P2 - P3 * P4;
            t4 = t4 + t4;
            v4f na = s4 - t4, nb = s4 + t4;
            float sa0 = fsqrt(fmaxf(na[0], 1e-8f));
            float sa1 = fsqrt(fmaxf(na[1], 1e-8f));
            float sa2 = fsqrt(fmaxf(na[2], 1e-8f));
            float sa3 = fsqrt(fmaxf(na[3], 1e-8f));
            float sb0 = fsqrt(fmaxf(nb[0], 1e-8f));
            float sb1 = fsqrt(fmaxf(nb[1], 1e-8f));
            float sb2 = fsqrt(fmaxf(nb[2], 1e-8f));
            float sb3 = fsqrt(fmaxf(nb[3], 1e-8f));
            float ma = (sa0 + sa1) + (sa2 + sa3);
            float mb = (sb0 + sb1) + (sb2 + sb3);
            // 4-level dpp reduce: every lane of each 16-group holds its
            // group sum; groups write partials, epilogue sums 4.
            ma = dpp_add<0xB1>(ma);   mb = dpp_add<0xB1>(mb);   // quad_perm xor1
            ma = dpp_add<0x4E>(ma);   mb = dpp_add<0x4E>(mb);   // quad_perm xor2
            ma = dpp_add<0x141>(ma);  mb = dpp_add<0x141>(mb);  // row_half_mirror
            ma = dpp_add<0x140>(ma);  mb = dpp_add<0x140>(mb);  // row_mirror
            if ((lane & 15) == 0) {
                s1st4[(fa  * 16 + r4 * 4 + nt) * 4 + grp] = ma;
                s1st4[(fbi * 16 + r4 * 4 + nt) * 4 + grp] = mb;
            }
        }

        // ---- pass A(p+1): gray . G -> T[(p+1)&1]; then F(p+1) loads ----
        if (p < NPAIR - 1) {
            #pragma unroll
            for (int mi = 0; mi < 3; ++mi) {
                int mt = half * 3 + mi;
                v4f aR = {0.f, 0.f, 0.f, 0.f}, aI = {0.f, 0.f, 0.f, 0.f};
                #pragma unroll
                for (int j = 0; j < 2; ++j) {
                    aR = __builtin_amdgcn_mfma_f32_16x16x32_f16(Agray[mi][j], Gre[j], aR, 0, 0, 0);
                    aI = __builtin_amdgcn_mfma_f32_16x16x32_f16(Agray[mi][j], Gim[j], aI, 0, 0, 0);
                }
                int mb = mt * 16 + q4;
                uint2 pr, pi;
                pr.x = pkrtz(aR[0], aR[1]);  pr.y = pkrtz(aR[2], aR[3]);
                pi.x = pkrtz(aI[0], aI[1]);  pi.y = pkrtz(aI[2], aI[3]);
                *(uint2*)(&Trn[cr * GS + mb]) = pr;
                *(uint2*)(&Tin[cr * GS + mb]) = pi;
            }
            // F(p+1) prefetch: latency spans the lgkm-barrier
            #pragma unroll
            for (int j = 0; j < 2; ++j) {
                int idx = (b0 + j) * 4;
                Fre[j] = ldfrag(fbn + 320 + idx);
                Fim[j] = ldfrag(fbn + 480 + idx);
            }
        }
        bar_lgkm();             // T + s1st4 ds ops drained; globals in flight
    }

    // ---- epilogue: sum 4 group-partials per output, store S1 ----
    // (loop ended with bar_lgkm -> all s1st4 writes visible)
    float* s1b = s1out + (size_t)n * NFILT * 32 * 32;
    for (int e = tid; e < NFILT * 16; e += 512) {
        int fi = e >> 4, cell = e & 15;
        int r4c = cell >> 2, ntc = cell & 3;
        v4f pp = *(const v4f*)(&s1st4[e * 4]);
        float s = (pp[0] + pp[1]) + (pp[2] + pp[3]);
        s1b[((size_t)fi * 32 + (ty * 4 + r4c)) * 32 + (tx * 4 + ntc)] =
            s * (1.0f / 256.0f);
    }
}

// ---------------------------------------------------------------------------
extern "C" void kernel_launch(void* const* d_in, const int* in_sizes, int n_in,
                              void* d_out, int out_size, void* d_ws, size_t ws_size,
                              hipStream_t stream) {
    const float* x = (const float*)d_in[0];
    float* out = (float*)d_out;
    unsigned* tabs = (unsigned*)d_ws;          // 102400 dwords = 400 KB scratch

    hipLaunchKernelGGL(make_tables, dim3(32), dim3(256), 0, stream, tabs);
    hipLaunchKernelGGL(conv_kernel, dim3(512), dim3(512), 0, stream,
                       x, (const uint4*)tabs, out, out + 8192);
}